// Round 1
// baseline (2601.957 us; speedup 1.0000x reference)
//
#include <hip/hip_runtime.h>
#include <hip/hip_bf16.h>

#define N_NODES 20000
#define N_EDGES 640000
#define N_HIDDEN 128
#define EDGE_DIM 8
#define NODE_DIM 16
#define N_BLOCKS 15
#define N_BINARY 10

// ---------------- embed: h = log(x+1) @ embW + embB ; x2 = h/std(h) ----------
__global__ void k_embed(const float* __restrict__ x, const float* __restrict__ eW,
                        const float* __restrict__ eb, float* __restrict__ h,
                        float* __restrict__ x2) {
  int wid = (blockIdx.x * blockDim.x + threadIdx.x) >> 6;  // one wave per node
  int lane = threadIdx.x & 63;
  if (wid >= N_NODES) return;
  float xl[NODE_DIM];
#pragma unroll
  for (int k = 0; k < NODE_DIM; k++) xl[k] = logf(x[wid * NODE_DIM + k] + 1.0f);
  int c0 = lane, c1 = lane + 64;
  float h0 = eb[c0], h1 = eb[c1];
#pragma unroll
  for (int k = 0; k < NODE_DIM; k++) {
    h0 += xl[k] * eW[k * N_HIDDEN + c0];
    h1 += xl[k] * eW[k * N_HIDDEN + c1];
  }
  float ss = h0 + h1, s2 = h0 * h0 + h1 * h1;
#pragma unroll
  for (int m = 1; m < 64; m <<= 1) {
    ss += __shfl_xor(ss, m);
    s2 += __shfl_xor(s2, m);
  }
  // torch std: unbiased (ddof=1), includes mean subtraction
  float var = (s2 - ss * ss * (1.0f / 128.0f)) * (1.0f / 127.0f);
  float inv = 1.0f / sqrtf(var);
  size_t o = (size_t)wid * N_HIDDEN;
  h[o + c0] = h0;
  h[o + c1] = h1;
  x2[o + c0] = h0 * inv;
  x2[o + c1] = h1 * inv;
}

// ---------------- CSR build ----------------
__global__ void k_count(const int* __restrict__ ei, int* __restrict__ deg) {
  int e = blockIdx.x * blockDim.x + threadIdx.x;
  if (e < N_EDGES) atomicAdd(&deg[ei[N_EDGES + e]], 1);  // dst row
}

__global__ void k_scan(const int* __restrict__ deg, int* __restrict__ off,
                       int* __restrict__ cur) {
  __shared__ int buf[256];
  __shared__ int carry_s;
  int tid = threadIdx.x;
  if (tid == 0) carry_s = 0;
  __syncthreads();
  for (int base = 0; base < N_NODES; base += 256) {
    int i = base + tid;
    int v = (i < N_NODES) ? deg[i] : 0;
    buf[tid] = v;
    __syncthreads();
    for (int s = 1; s < 256; s <<= 1) {  // Hillis-Steele inclusive scan
      int t = (tid >= s) ? buf[tid - s] : 0;
      __syncthreads();
      buf[tid] += t;
      __syncthreads();
    }
    int incl = buf[tid];
    int carry = carry_s;
    if (i < N_NODES) {
      int e = carry + incl - v;  // exclusive
      off[i] = e;
      cur[i] = e;
    }
    __syncthreads();
    if (tid == 0) carry_s = carry + buf[255];
    __syncthreads();
  }
  if (tid == 0) off[N_NODES] = carry_s;
}

// permute edges into dst-sorted order; fuse log(edge_attr + 1)
__global__ void k_permute(const int* __restrict__ ei, const float* __restrict__ eattr,
                          int* __restrict__ cur, int* __restrict__ src_s,
                          float* __restrict__ ea_s) {
  int e = blockIdx.x * blockDim.x + threadIdx.x;
  if (e >= N_EDGES) return;
  int d = ei[N_EDGES + e];
  int s = ei[e];
  int pos = atomicAdd(&cur[d], 1);
  src_s[pos] = s;
  const float4* ap = (const float4*)(eattr + (size_t)e * 8);
  float4 a0 = ap[0], a1 = ap[1];
  float4 r0 = make_float4(logf(a0.x + 1.0f), logf(a0.y + 1.0f),
                          logf(a0.z + 1.0f), logf(a0.w + 1.0f));
  float4 r1 = make_float4(logf(a1.x + 1.0f), logf(a1.y + 1.0f),
                          logf(a1.z + 1.0f), logf(a1.w + 1.0f));
  float4* dp = (float4*)(ea_s + (size_t)pos * 8);
  dp[0] = r0;
  dp[1] = r1;
}

// -------- per-block message+aggregate: z = x2 + sum_{e->n} relu(x2[src]+ea@eW+eb) --------
__global__ void k_msg(const int* __restrict__ off, const int* __restrict__ src_s,
                      const float* __restrict__ ea_s, const float* __restrict__ x2,
                      const float* __restrict__ eW, const float* __restrict__ eb,
                      float* __restrict__ z) {
  int wid = (blockIdx.x * blockDim.x + threadIdx.x) >> 6;  // one wave per node
  int lane = threadIdx.x & 63;
  if (wid >= N_NODES) return;
  int c0 = lane, c1 = lane + 64;
  float w0[EDGE_DIM], w1[EDGE_DIM];
#pragma unroll
  for (int k = 0; k < EDGE_DIM; k++) {
    w0[k] = eW[k * N_HIDDEN + c0];
    w1[k] = eW[k * N_HIDDEN + c1];
  }
  float bb0 = eb[c0], bb1 = eb[c1];
  float acc0 = 0.f, acc1 = 0.f;
  int eBeg = off[wid], eEnd = off[wid + 1];
  for (int e = eBeg; e < eEnd; ++e) {
    int s = src_s[e];
    const float4* ap = (const float4*)(ea_s + (size_t)e * 8);
    float4 a0 = ap[0], a1 = ap[1];
    float v0 = bb0 + a0.x * w0[0] + a0.y * w0[1] + a0.z * w0[2] + a0.w * w0[3] +
               a1.x * w0[4] + a1.y * w0[5] + a1.z * w0[6] + a1.w * w0[7];
    float v1 = bb1 + a0.x * w1[0] + a0.y * w1[1] + a0.z * w1[2] + a0.w * w1[3] +
               a1.x * w1[4] + a1.y * w1[5] + a1.z * w1[6] + a1.w * w1[7];
    size_t so = (size_t)s * N_HIDDEN;
    float m0 = x2[so + c0] + v0;
    float m1 = x2[so + c1] + v1;
    acc0 += fmaxf(m0, 0.f);
    acc1 += fmaxf(m1, 0.f);
  }
  size_t o = (size_t)wid * N_HIDDEN;
  z[o + c0] = x2[o + c0] + acc0;
  z[o + c1] = x2[o + c1] + acc1;
}

// -------- per-block MLP: z -> relu(zW1+b1) -> relu(..W2+b2) -> ..W3+b3 -> y=z3/std; h+=y; x2=h/std --------
__device__ __forceinline__ void mlp_layer(float (*zb)[128], float (*wb)[128],
                                          const float* __restrict__ W,
                                          const float* __restrict__ bias, bool relu,
                                          int tid) {
  int tj = tid & 15, ti = tid >> 4;
  int r0 = ti * 4, cc = tj * 8;
  float acc[4][8];
#pragma unroll
  for (int i = 0; i < 4; i++)
#pragma unroll
    for (int j = 0; j < 8; j++) acc[i][j] = bias[cc + j];
  for (int kh = 0; kh < 2; kh++) {
    __syncthreads();  // wb free to overwrite (also fences zb producer)
    for (int idx = tid; idx < 64 * 128; idx += 256) {
      int kk = idx >> 7, c = idx & 127;
      wb[kk][c] = W[(size_t)(kh * 64 + kk) * 128 + c];
    }
    __syncthreads();
#pragma unroll 4
    for (int kk = 0; kk < 64; kk++) {
      int k = kh * 64 + kk;
      float za[4];
#pragma unroll
      for (int i = 0; i < 4; i++) za[i] = zb[r0 + i][k];
      float4 wv0 = *(const float4*)&wb[kk][cc];
      float4 wv1 = *(const float4*)&wb[kk][cc + 4];
#pragma unroll
      for (int i = 0; i < 4; i++) {
        acc[i][0] += za[i] * wv0.x;
        acc[i][1] += za[i] * wv0.y;
        acc[i][2] += za[i] * wv0.z;
        acc[i][3] += za[i] * wv0.w;
        acc[i][4] += za[i] * wv1.x;
        acc[i][5] += za[i] * wv1.y;
        acc[i][6] += za[i] * wv1.z;
        acc[i][7] += za[i] * wv1.w;
      }
    }
  }
  __syncthreads();
#pragma unroll
  for (int i = 0; i < 4; i++)
#pragma unroll
    for (int j = 0; j < 8; j++) {
      float v = acc[i][j];
      if (relu) v = fmaxf(v, 0.f);
      zb[r0 + i][cc + j] = v;
    }
  __syncthreads();
}

__global__ __launch_bounds__(256) void k_mlp(const float* __restrict__ z,
                                             const float* __restrict__ W1,
                                             const float* __restrict__ b1,
                                             const float* __restrict__ W2,
                                             const float* __restrict__ b2,
                                             const float* __restrict__ W3,
                                             const float* __restrict__ b3,
                                             float* __restrict__ h,
                                             float* __restrict__ x2) {
  __shared__ float zb[64][128];
  __shared__ float wb[64][128];
  int tid = threadIdx.x;
  int g0 = blockIdx.x * 64;
  for (int idx = tid; idx < 64 * 128; idx += 256) {
    int n = idx >> 7, c = idx & 127;
    int g = g0 + n;
    zb[n][c] = (g < N_NODES) ? z[(size_t)g * 128 + c] : 0.0f;
  }
  mlp_layer(zb, wb, W1, b1, true, tid);
  mlp_layer(zb, wb, W2, b2, true, tid);
  mlp_layer(zb, wb, W3, b3, false, tid);
  // epilogue: wave per node
  int w = tid >> 6, lane = tid & 63;
  for (int it = 0; it < 16; ++it) {
    int n = it * 4 + w;
    int g = g0 + n;
    if (g < N_NODES) {
      float z0 = zb[n][lane], z1 = zb[n][lane + 64];
      float ss = z0 + z1, s2 = z0 * z0 + z1 * z1;
#pragma unroll
      for (int m = 1; m < 64; m <<= 1) {
        ss += __shfl_xor(ss, m);
        s2 += __shfl_xor(s2, m);
      }
      float inv = 1.0f / sqrtf((s2 - ss * ss * (1.0f / 128.0f)) * (1.0f / 127.0f));
      size_t o = (size_t)g * 128;
      float h0 = h[o + lane] + z0 * inv;
      float h1 = h[o + lane + 64] + z1 * inv;
      float ts = h0 + h1, t2 = h0 * h0 + h1 * h1;
#pragma unroll
      for (int m = 1; m < 64; m <<= 1) {
        ts += __shfl_xor(ts, m);
        t2 += __shfl_xor(t2, m);
      }
      float inv2 = 1.0f / sqrtf((t2 - ts * ts * (1.0f / 128.0f)) * (1.0f / 127.0f));
      h[o + lane] = h0;
      h[o + lane + 64] = h1;
      x2[o + lane] = h0 * inv2;
      x2[o + lane + 64] = h1 * inv2;
    }
  }
}

// -------- output: out[n] = dot(h/sqrt(15), outW @ 2^j) + dot(outB, 2^j) --------
__global__ void k_out(const float* __restrict__ h, const float* __restrict__ oW,
                      const float* __restrict__ ob, float* __restrict__ out) {
  int wid = (blockIdx.x * blockDim.x + threadIdx.x) >> 6;
  int lane = threadIdx.x & 63;
  if (wid >= N_NODES) return;
  int c0 = lane, c1 = lane + 64;
  float w0 = 0.f, w1 = 0.f, bsum = 0.f;
#pragma unroll
  for (int j = 0; j < N_BINARY; j++) {
    float sc = (float)(1 << j);
    w0 += oW[c0 * N_BINARY + j] * sc;
    w1 += oW[c1 * N_BINARY + j] * sc;
    bsum += ob[j] * sc;
  }
  size_t o = (size_t)wid * 128;
  float v = h[o + c0] * w0 + h[o + c1] * w1;
#pragma unroll
  for (int m = 1; m < 64; m <<= 1) v += __shfl_xor(v, m);
  if (lane == 0) out[wid] = v * (1.0f / sqrtf(15.0f)) + bsum;
}

extern "C" void kernel_launch(void* const* d_in, const int* in_sizes, int n_in,
                              void* d_out, int out_size, void* d_ws, size_t ws_size,
                              hipStream_t stream) {
  const float* x = (const float*)d_in[0];
  const int* ei = (const int*)d_in[1];
  const float* eattr = (const float*)d_in[2];
  const float* embW = (const float*)d_in[3];
  const float* embB = (const float*)d_in[4];
  const float* edgeW = (const float*)d_in[5];
  const float* edgeB = (const float*)d_in[6];
  const float* W1 = (const float*)d_in[7];
  const float* b1 = (const float*)d_in[8];
  const float* W2 = (const float*)d_in[9];
  const float* b2 = (const float*)d_in[10];
  const float* W3 = (const float*)d_in[11];
  const float* b3 = (const float*)d_in[12];
  const float* outW = (const float*)d_in[13];
  const float* outB = (const float*)d_in[14];
  float* out = (float*)d_out;

  char* base = (char*)d_ws;
  size_t o = 0;
  auto carve = [&](size_t bytes) {
    size_t start = o;
    o = (start + bytes + 255) & ~(size_t)255;
    return (void*)(base + start);
  };
  int* deg = (int*)carve(N_NODES * sizeof(int));
  int* off = (int*)carve((N_NODES + 1) * sizeof(int));
  int* cur = (int*)carve(N_NODES * sizeof(int));
  int* src_s = (int*)carve(N_EDGES * sizeof(int));
  float* ea_s = (float*)carve((size_t)N_EDGES * EDGE_DIM * sizeof(float));
  float* h = (float*)carve((size_t)N_NODES * N_HIDDEN * sizeof(float));
  float* x2 = (float*)carve((size_t)N_NODES * N_HIDDEN * sizeof(float));
  float* z = (float*)carve((size_t)N_NODES * N_HIDDEN * sizeof(float));

  hipMemsetAsync(deg, 0, N_NODES * sizeof(int), stream);
  k_embed<<<N_NODES / 4, 256, 0, stream>>>(x, embW, embB, h, x2);
  k_count<<<(N_EDGES + 255) / 256, 256, 0, stream>>>(ei, deg);
  k_scan<<<1, 256, 0, stream>>>(deg, off, cur);
  k_permute<<<(N_EDGES + 255) / 256, 256, 0, stream>>>(ei, eattr, cur, src_s, ea_s);

  for (int b = 0; b < N_BLOCKS; b++) {
    k_msg<<<N_NODES / 4, 256, 0, stream>>>(off, src_s, ea_s, x2,
                                           edgeW + (size_t)b * EDGE_DIM * N_HIDDEN,
                                           edgeB + (size_t)b * N_HIDDEN, z);
    k_mlp<<<(N_NODES + 63) / 64, 256, 0, stream>>>(
        z, W1 + (size_t)b * N_HIDDEN * N_HIDDEN, b1 + (size_t)b * N_HIDDEN,
        W2 + (size_t)b * N_HIDDEN * N_HIDDEN, b2 + (size_t)b * N_HIDDEN,
        W3 + (size_t)b * N_HIDDEN * N_HIDDEN, b3 + (size_t)b * N_HIDDEN, h, x2);
  }
  k_out<<<N_NODES / 4, 256, 0, stream>>>(h, outW, outB, out);
}

// Round 2
// 1606.701 us; speedup vs baseline: 1.6194x; 1.6194x over previous
//
#include <hip/hip_runtime.h>
#include <hip/hip_bf16.h>

#define N_NODES 20000
#define N_EDGES 640000
#define N_HIDDEN 128
#define EDGE_DIM 8
#define NODE_DIM 16
#define N_BLOCKS 15
#define N_BINARY 10

typedef __attribute__((ext_vector_type(8))) short bf16x8;
typedef __attribute__((ext_vector_type(4))) float f32x4;

static __device__ __forceinline__ float bf2fs(unsigned short u) {
  union { unsigned int i; float f; } v; v.i = (unsigned int)u << 16; return v.f;
}
static __device__ __forceinline__ float bf2fl(unsigned int u) {
  union { unsigned int i; float f; } v; v.i = u << 16; return v.f;
}
static __device__ __forceinline__ float bf2fh(unsigned int u) {
  union { unsigned int i; float f; } v; v.i = u & 0xffff0000u; return v.f;
}
static __device__ __forceinline__ unsigned short f2bf(float f) {  // RNE
  unsigned int x = __float_as_uint(f);
  x += 0x7fffu + ((x >> 16) & 1u);
  return (unsigned short)(x >> 16);
}

// ---------------- embed: h = log(x+1) @ embW + embB ; x2b = bf16(h/std(h)) ---
__global__ void k_embed(const float* __restrict__ x, const float* __restrict__ eW,
                        const float* __restrict__ ebias, float* __restrict__ h,
                        unsigned short* __restrict__ x2b) {
  int wid = (blockIdx.x * blockDim.x + threadIdx.x) >> 6;
  int lane = threadIdx.x & 63;
  if (wid >= N_NODES) return;
  float xl[NODE_DIM];
#pragma unroll
  for (int k = 0; k < NODE_DIM; k++) xl[k] = logf(x[wid * NODE_DIM + k] + 1.0f);
  int c0 = lane, c1 = lane + 64;
  float h0 = ebias[c0], h1 = ebias[c1];
#pragma unroll
  for (int k = 0; k < NODE_DIM; k++) {
    h0 += xl[k] * eW[k * N_HIDDEN + c0];
    h1 += xl[k] * eW[k * N_HIDDEN + c1];
  }
  float ss = h0 + h1, s2 = h0 * h0 + h1 * h1;
#pragma unroll
  for (int m = 1; m < 64; m <<= 1) {
    ss += __shfl_xor(ss, m);
    s2 += __shfl_xor(s2, m);
  }
  float var = (s2 - ss * ss * (1.0f / 128.0f)) * (1.0f / 127.0f);
  float inv = 1.0f / sqrtf(var);
  size_t o = (size_t)wid * N_HIDDEN;
  h[o + c0] = h0;
  h[o + c1] = h1;
  x2b[o + c0] = f2bf(h0 * inv);
  x2b[o + c1] = f2bf(h1 * inv);
}

// ---------------- CSR build ----------------
__global__ void k_count(const int* __restrict__ ei, int* __restrict__ deg) {
  int e = blockIdx.x * blockDim.x + threadIdx.x;
  if (e < N_EDGES) atomicAdd(&deg[ei[N_EDGES + e]], 1);
}

__global__ void k_scan(const int* __restrict__ deg, int* __restrict__ off,
                       int* __restrict__ cur) {
  __shared__ int buf[256];
  __shared__ int carry_s;
  int tid = threadIdx.x;
  if (tid == 0) carry_s = 0;
  __syncthreads();
  for (int base = 0; base < N_NODES; base += 256) {
    int i = base + tid;
    int v = (i < N_NODES) ? deg[i] : 0;
    buf[tid] = v;
    __syncthreads();
    for (int s = 1; s < 256; s <<= 1) {
      int t = (tid >= s) ? buf[tid - s] : 0;
      __syncthreads();
      buf[tid] += t;
      __syncthreads();
    }
    int incl = buf[tid];
    int carry = carry_s;
    if (i < N_NODES) {
      int e = carry + incl - v;
      off[i] = e;
      cur[i] = e;
    }
    __syncthreads();
    if (tid == 0) carry_s = carry + buf[255];
    __syncthreads();
  }
  if (tid == 0) off[N_NODES] = carry_s;
}

// permute edges into dst-sorted order; fuse log(edge_attr+1) -> bf16
__global__ void k_permute(const int* __restrict__ ei, const float* __restrict__ eattr,
                          int* __restrict__ cur, int* __restrict__ src_s,
                          unsigned short* __restrict__ ea_b) {
  int e = blockIdx.x * blockDim.x + threadIdx.x;
  if (e >= N_EDGES) return;
  int d = ei[N_EDGES + e];
  int s = ei[e];
  int pos = atomicAdd(&cur[d], 1);
  src_s[pos] = s;
  const float4* ap = (const float4*)(eattr + (size_t)e * 8);
  float4 a0 = ap[0], a1 = ap[1];
  unsigned int p0 = (unsigned int)f2bf(logf(a0.x + 1.0f)) |
                    ((unsigned int)f2bf(logf(a0.y + 1.0f)) << 16);
  unsigned int p1 = (unsigned int)f2bf(logf(a0.z + 1.0f)) |
                    ((unsigned int)f2bf(logf(a0.w + 1.0f)) << 16);
  unsigned int p2 = (unsigned int)f2bf(logf(a1.x + 1.0f)) |
                    ((unsigned int)f2bf(logf(a1.y + 1.0f)) << 16);
  unsigned int p3 = (unsigned int)f2bf(logf(a1.z + 1.0f)) |
                    ((unsigned int)f2bf(logf(a1.w + 1.0f)) << 16);
  *(uint4*)(ea_b + (size_t)pos * 8) = make_uint4(p0, p1, p2, p3);
}

// ---------------- weight transpose+bf16: Wt[m][n][k] = W[m..][k][n] ----------
__global__ void k_prep_w(const float* __restrict__ W1, const float* __restrict__ W2,
                         const float* __restrict__ W3, unsigned short* __restrict__ Wt) {
  __shared__ unsigned short t[128][130];
  int m = blockIdx.x;  // 0..44 = blk*3+layer
  int blk = m / 3, layer = m % 3;
  const float* src = (layer == 0 ? W1 : layer == 1 ? W2 : W3) + (size_t)blk * 16384;
  int tid = threadIdx.x;
  for (int idx = tid; idx < 16384; idx += 256) {
    int k = idx >> 7, n = idx & 127;
    t[k][n] = f2bf(src[idx]);
  }
  __syncthreads();
  unsigned short* dst = Wt + (size_t)m * 16384;
  for (int idx = tid; idx < 16384; idx += 256) {
    int n = idx >> 7, k = idx & 127;
    dst[idx] = t[k][n];
  }
}

// -------- per-block message+aggregate (bf16 gather, fp32 math) --------
__global__ __launch_bounds__(256) void k_msg(
    const int* __restrict__ off, const int* __restrict__ src_s,
    const unsigned short* __restrict__ ea_b, const unsigned short* __restrict__ x2b,
    const float* __restrict__ eW, const float* __restrict__ ebias,
    unsigned short* __restrict__ z_b) {
  int wid = (blockIdx.x * blockDim.x + threadIdx.x) >> 6;
  int lane = threadIdx.x & 63;
  if (wid >= N_NODES) return;
  int c0 = lane, c1 = lane + 64;
  float w0[EDGE_DIM], w1[EDGE_DIM];
#pragma unroll
  for (int k = 0; k < EDGE_DIM; k++) {
    w0[k] = eW[k * N_HIDDEN + c0];
    w1[k] = eW[k * N_HIDDEN + c1];
  }
  float bb0 = ebias[c0], bb1 = ebias[c1];
  float acc0 = 0.f, acc1 = 0.f;
  int eBeg = off[wid], eEnd = off[wid + 1];

#define EDGE_BODY(EE)                                                          \
  {                                                                            \
    int s = src_s[EE];                                                         \
    uint4 ev = *(const uint4*)(ea_b + (size_t)(EE)*8);                         \
    size_t so = (size_t)s * N_HIDDEN;                                          \
    unsigned short ua = x2b[so + c0], ub = x2b[so + c1];                       \
    float e0 = bf2fl(ev.x), e1 = bf2fh(ev.x), e2 = bf2fl(ev.y),                \
          e3 = bf2fh(ev.y), e4 = bf2fl(ev.z), e5 = bf2fh(ev.z),                \
          e6 = bf2fl(ev.w), e7 = bf2fh(ev.w);                                  \
    float v0 = bb0 + e0 * w0[0] + e1 * w0[1] + e2 * w0[2] + e3 * w0[3] +       \
               e4 * w0[4] + e5 * w0[5] + e6 * w0[6] + e7 * w0[7];              \
    float v1 = bb1 + e0 * w1[0] + e1 * w1[1] + e2 * w1[2] + e3 * w1[3] +       \
               e4 * w1[4] + e5 * w1[5] + e6 * w1[6] + e7 * w1[7];              \
    acc0 += fmaxf(bf2fs(ua) + v0, 0.f);                                        \
    acc1 += fmaxf(bf2fs(ub) + v1, 0.f);                                        \
  }

  int e = eBeg;
  for (; e + 1 < eEnd; e += 2) {
    EDGE_BODY(e);
    EDGE_BODY(e + 1);
  }
  for (; e < eEnd; ++e) EDGE_BODY(e);
#undef EDGE_BODY

  size_t o = (size_t)wid * N_HIDDEN;
  z_b[o + c0] = f2bf(bf2fs(x2b[o + c0]) + acc0);
  z_b[o + c1] = f2bf(bf2fs(x2b[o + c1]) + acc1);
}

// -------- MFMA MLP: 64 nodes/block, 4 waves, wave owns 16 rows ---------------
__global__ __launch_bounds__(256) void k_mlp(
    const unsigned short* __restrict__ z_b, const unsigned short* __restrict__ Wt,
    const float* __restrict__ b1, const float* __restrict__ b2,
    const float* __restrict__ b3, float* __restrict__ h,
    unsigned short* __restrict__ x2b) {
  __shared__ __align__(16) short lz[4][16][136];  // per-wave private, pitch 136
  int tid = threadIdx.x;
  int w = tid >> 6, lane = tid & 63;
  int l15 = lane & 15, g = lane >> 4;
  int g0 = blockIdx.x * 64;
  int nodeA = g0 + w * 16 + l15;
  int nodeAc = min(nodeA, N_NODES - 1);

  f32x4 acc[8];
  bf16x8 a[4];

  // ---- layer 1: A from global z_b ----
#pragma unroll
  for (int kk = 0; kk < 4; kk++)
    a[kk] = *(const bf16x8*)(z_b + (size_t)nodeAc * 128 + kk * 32 + g * 8);
#pragma unroll
  for (int c = 0; c < 8; c++) {
    float bv = b1[c * 16 + l15];
    acc[c] = (f32x4){bv, bv, bv, bv};
  }
#pragma unroll
  for (int c = 0; c < 8; c++) {
#pragma unroll
    for (int kk = 0; kk < 4; kk++) {
      bf16x8 bf = *(const bf16x8*)(Wt + (size_t)(c * 16 + l15) * 128 + kk * 32 + g * 8);
      acc[c] = __builtin_amdgcn_mfma_f32_16x16x32_bf16(a[kk], bf, acc[c], 0, 0, 0);
    }
  }
#pragma unroll
  for (int c = 0; c < 8; c++)
#pragma unroll
    for (int r = 0; r < 4; r++)
      lz[w][4 * g + r][c * 16 + l15] = (short)f2bf(fmaxf(acc[c][r], 0.f));
  __syncthreads();

  // ---- layer 2: A from LDS ----
#pragma unroll
  for (int kk = 0; kk < 4; kk++)
    a[kk] = *(const bf16x8*)&lz[w][l15][kk * 32 + g * 8];
#pragma unroll
  for (int c = 0; c < 8; c++) {
    float bv = b2[c * 16 + l15];
    acc[c] = (f32x4){bv, bv, bv, bv};
  }
  {
    const unsigned short* W2t = Wt + 16384;
#pragma unroll
    for (int c = 0; c < 8; c++) {
#pragma unroll
      for (int kk = 0; kk < 4; kk++) {
        bf16x8 bf = *(const bf16x8*)(W2t + (size_t)(c * 16 + l15) * 128 + kk * 32 + g * 8);
        acc[c] = __builtin_amdgcn_mfma_f32_16x16x32_bf16(a[kk], bf, acc[c], 0, 0, 0);
      }
    }
  }
  __syncthreads();
#pragma unroll
  for (int c = 0; c < 8; c++)
#pragma unroll
    for (int r = 0; r < 4; r++)
      lz[w][4 * g + r][c * 16 + l15] = (short)f2bf(fmaxf(acc[c][r], 0.f));
  __syncthreads();

  // ---- layer 3 (no relu) ----
#pragma unroll
  for (int kk = 0; kk < 4; kk++)
    a[kk] = *(const bf16x8*)&lz[w][l15][kk * 32 + g * 8];
#pragma unroll
  for (int c = 0; c < 8; c++) {
    float bv = b3[c * 16 + l15];
    acc[c] = (f32x4){bv, bv, bv, bv};
  }
  {
    const unsigned short* W3t = Wt + 32768;
#pragma unroll
    for (int c = 0; c < 8; c++) {
#pragma unroll
      for (int kk = 0; kk < 4; kk++) {
        bf16x8 bf = *(const bf16x8*)(W3t + (size_t)(c * 16 + l15) * 128 + kk * 32 + g * 8);
        acc[c] = __builtin_amdgcn_mfma_f32_16x16x32_bf16(a[kk], bf, acc[c], 0, 0, 0);
      }
    }
  }

  // ---- epilogue: y = z3/std; h += y; x2b = bf16(h/std(h)) ----
  // C/D layout: col = 16c + l15, row(node offset) = 4g + r
  float s1[4] = {0.f, 0.f, 0.f, 0.f}, s2[4] = {0.f, 0.f, 0.f, 0.f};
#pragma unroll
  for (int c = 0; c < 8; c++)
#pragma unroll
    for (int r = 0; r < 4; r++) {
      float v = acc[c][r];
      s1[r] += v;
      s2[r] += v * v;
    }
#pragma unroll
  for (int m = 1; m < 16; m <<= 1)
#pragma unroll
    for (int r = 0; r < 4; r++) {
      s1[r] += __shfl_xor(s1[r], m);
      s2[r] += __shfl_xor(s2[r], m);
    }
  float inv[4];
#pragma unroll
  for (int r = 0; r < 4; r++)
    inv[r] = 1.0f / sqrtf((s2[r] - s1[r] * s1[r] * (1.0f / 128.0f)) * (1.0f / 127.0f));

  int nodeE = g0 + w * 16 + 4 * g;
  float t1[4] = {0.f, 0.f, 0.f, 0.f}, t2[4] = {0.f, 0.f, 0.f, 0.f};
#pragma unroll
  for (int c = 0; c < 8; c++)
#pragma unroll
    for (int r = 0; r < 4; r++) {
      int n = nodeE + r;
      int nc = min(n, N_NODES - 1);
      float hv = h[(size_t)nc * 128 + c * 16 + l15] + acc[c][r] * inv[r];
      acc[c][r] = hv;
      t1[r] += hv;
      t2[r] += hv * hv;
    }
#pragma unroll
  for (int m = 1; m < 16; m <<= 1)
#pragma unroll
    for (int r = 0; r < 4; r++) {
      t1[r] += __shfl_xor(t1[r], m);
      t2[r] += __shfl_xor(t2[r], m);
    }
  float inv2[4];
#pragma unroll
  for (int r = 0; r < 4; r++)
    inv2[r] = 1.0f / sqrtf((t2[r] - t1[r] * t1[r] * (1.0f / 128.0f)) * (1.0f / 127.0f));

#pragma unroll
  for (int c = 0; c < 8; c++)
#pragma unroll
    for (int r = 0; r < 4; r++) {
      int n = nodeE + r;
      if (n < N_NODES) {
        size_t idx = (size_t)n * 128 + c * 16 + l15;
        h[idx] = acc[c][r];
        x2b[idx] = f2bf(acc[c][r] * inv2[r]);
      }
    }
}

// -------- output --------
__global__ void k_out(const float* __restrict__ h, const float* __restrict__ oW,
                      const float* __restrict__ ob, float* __restrict__ out) {
  int wid = (blockIdx.x * blockDim.x + threadIdx.x) >> 6;
  int lane = threadIdx.x & 63;
  if (wid >= N_NODES) return;
  int c0 = lane, c1 = lane + 64;
  float w0 = 0.f, w1 = 0.f, bsum = 0.f;
#pragma unroll
  for (int j = 0; j < N_BINARY; j++) {
    float sc = (float)(1 << j);
    w0 += oW[c0 * N_BINARY + j] * sc;
    w1 += oW[c1 * N_BINARY + j] * sc;
    bsum += ob[j] * sc;
  }
  size_t o = (size_t)wid * 128;
  float v = h[o + c0] * w0 + h[o + c1] * w1;
#pragma unroll
  for (int m = 1; m < 64; m <<= 1) v += __shfl_xor(v, m);
  if (lane == 0) out[wid] = v * (1.0f / sqrtf(15.0f)) + bsum;
}

extern "C" void kernel_launch(void* const* d_in, const int* in_sizes, int n_in,
                              void* d_out, int out_size, void* d_ws, size_t ws_size,
                              hipStream_t stream) {
  const float* x = (const float*)d_in[0];
  const int* ei = (const int*)d_in[1];
  const float* eattr = (const float*)d_in[2];
  const float* embW = (const float*)d_in[3];
  const float* embB = (const float*)d_in[4];
  const float* edgeW = (const float*)d_in[5];
  const float* edgeB = (const float*)d_in[6];
  const float* W1 = (const float*)d_in[7];
  const float* b1 = (const float*)d_in[8];
  const float* W2 = (const float*)d_in[9];
  const float* b2 = (const float*)d_in[10];
  const float* W3 = (const float*)d_in[11];
  const float* b3 = (const float*)d_in[12];
  const float* outW = (const float*)d_in[13];
  const float* outB = (const float*)d_in[14];
  float* out = (float*)d_out;

  char* base = (char*)d_ws;
  size_t o = 0;
  auto carve = [&](size_t bytes) {
    size_t start = o;
    o = (start + bytes + 255) & ~(size_t)255;
    return (void*)(base + start);
  };
  int* deg = (int*)carve(N_NODES * sizeof(int));
  int* off = (int*)carve((N_NODES + 1) * sizeof(int));
  int* cur = (int*)carve(N_NODES * sizeof(int));
  int* src_s = (int*)carve(N_EDGES * sizeof(int));
  unsigned short* ea_b = (unsigned short*)carve((size_t)N_EDGES * EDGE_DIM * 2);
  unsigned short* x2b = (unsigned short*)carve((size_t)N_NODES * N_HIDDEN * 2);
  unsigned short* z_b = (unsigned short*)carve((size_t)N_NODES * N_HIDDEN * 2);
  float* h = (float*)carve((size_t)N_NODES * N_HIDDEN * sizeof(float));
  unsigned short* Wt = (unsigned short*)carve((size_t)45 * 16384 * 2);

  hipMemsetAsync(deg, 0, N_NODES * sizeof(int), stream);
  k_embed<<<N_NODES / 4, 256, 0, stream>>>(x, embW, embB, h, x2b);
  k_count<<<(N_EDGES + 255) / 256, 256, 0, stream>>>(ei, deg);
  k_scan<<<1, 256, 0, stream>>>(deg, off, cur);
  k_permute<<<(N_EDGES + 255) / 256, 256, 0, stream>>>(ei, eattr, cur, src_s, ea_b);
  k_prep_w<<<45, 256, 0, stream>>>(W1, W2, W3, Wt);

  for (int b = 0; b < N_BLOCKS; b++) {
    k_msg<<<N_NODES / 4, 256, 0, stream>>>(off, src_s, ea_b, x2b,
                                           edgeW + (size_t)b * EDGE_DIM * N_HIDDEN,
                                           edgeB + (size_t)b * N_HIDDEN, z_b);
    k_mlp<<<(N_NODES + 63) / 64, 256, 0, stream>>>(
        z_b, Wt + (size_t)b * 3 * 16384, b1 + (size_t)b * N_HIDDEN,
        b2 + (size_t)b * N_HIDDEN, b3 + (size_t)b * N_HIDDEN, h, x2b);
  }
  k_out<<<N_NODES / 4, 256, 0, stream>>>(h, outW, outB, out);
}

// Round 3
// 1583.333 us; speedup vs baseline: 1.6433x; 1.0148x over previous
//
#include <hip/hip_runtime.h>
#include <hip/hip_bf16.h>

#define N_NODES 20000
#define N_EDGES 640000
#define N_HIDDEN 128
#define EDGE_DIM 8
#define NODE_DIM 16
#define N_BLOCKS 15
#define N_BINARY 10

typedef __attribute__((ext_vector_type(8))) _Float16 f16x8;
typedef __attribute__((ext_vector_type(4))) float f32x4;

// ---------------- embed: h = log(x+1) @ embW + embB ; x2h = f16(h/std(h)) ---
__global__ void k_embed(const float* __restrict__ x, const float* __restrict__ eW,
                        const float* __restrict__ ebias, float* __restrict__ h,
                        _Float16* __restrict__ x2h) {
  int wid = (blockIdx.x * blockDim.x + threadIdx.x) >> 6;
  int lane = threadIdx.x & 63;
  if (wid >= N_NODES) return;
  float xl[NODE_DIM];
#pragma unroll
  for (int k = 0; k < NODE_DIM; k++) xl[k] = logf(x[wid * NODE_DIM + k] + 1.0f);
  int c0 = lane, c1 = lane + 64;
  float h0 = ebias[c0], h1 = ebias[c1];
#pragma unroll
  for (int k = 0; k < NODE_DIM; k++) {
    h0 += xl[k] * eW[k * N_HIDDEN + c0];
    h1 += xl[k] * eW[k * N_HIDDEN + c1];
  }
  float ss = h0 + h1, s2 = h0 * h0 + h1 * h1;
#pragma unroll
  for (int m = 1; m < 64; m <<= 1) {
    ss += __shfl_xor(ss, m);
    s2 += __shfl_xor(s2, m);
  }
  float var = (s2 - ss * ss * (1.0f / 128.0f)) * (1.0f / 127.0f);
  float inv = 1.0f / sqrtf(var);
  size_t o = (size_t)wid * N_HIDDEN;
  h[o + c0] = h0;
  h[o + c1] = h1;
  x2h[o + c0] = (_Float16)(h0 * inv);
  x2h[o + c1] = (_Float16)(h1 * inv);
}

// ---------------- CSR build ----------------
__global__ void k_count(const int* __restrict__ ei, int* __restrict__ deg) {
  int e = blockIdx.x * blockDim.x + threadIdx.x;
  if (e < N_EDGES) atomicAdd(&deg[ei[N_EDGES + e]], 1);
}

// single-WG shfl-based scan over 20000 ints (1024 thr x 20 elems)
__global__ __launch_bounds__(1024) void k_scan(const int* __restrict__ deg,
                                               int* __restrict__ off,
                                               int* __restrict__ cur) {
  __shared__ int wsum[16];
  int t = threadIdx.x;
  int lane = t & 63, w = t >> 6;
  int base = t * 20;
  int loc[20];
  int s = 0;
#pragma unroll
  for (int i = 0; i < 20; i++) {
    int idx = base + i;
    int d = (idx < N_NODES) ? deg[idx] : 0;
    loc[i] = s;
    s += d;
  }
  int incl = s;
#pragma unroll
  for (int m = 1; m < 64; m <<= 1) {
    int o = __shfl_up(incl, m);
    if (lane >= m) incl += o;
  }
  if (lane == 63) wsum[w] = incl;
  __syncthreads();
  if (w == 0) {
    int xv = (lane < 16) ? wsum[lane] : 0;
#pragma unroll
    for (int m = 1; m < 16; m <<= 1) {
      int o = __shfl_up(xv, m);
      if (lane >= m) xv += o;
    }
    if (lane < 16) wsum[lane] = xv;  // inclusive per-wave totals
  }
  __syncthreads();
  int woff = (w == 0) ? 0 : wsum[w - 1];
  int texcl = woff + incl - s;
#pragma unroll
  for (int i = 0; i < 20; i++) {
    int idx = base + i;
    if (idx < N_NODES) {
      int v = texcl + loc[i];
      off[idx] = v;
      cur[idx] = v;
    }
  }
  if (t == 0) off[N_NODES] = wsum[15];
}

// permute edges into dst-sorted order; fuse log(edge_attr+1) -> f16
__global__ void k_permute(const int* __restrict__ ei, const float* __restrict__ eattr,
                          int* __restrict__ cur, int* __restrict__ src_s,
                          _Float16* __restrict__ ea_h) {
  int e = blockIdx.x * blockDim.x + threadIdx.x;
  if (e >= N_EDGES) return;
  int d = ei[N_EDGES + e];
  int s = ei[e];
  int pos = atomicAdd(&cur[d], 1);
  src_s[pos] = s;
  const float4* ap = (const float4*)(eattr + (size_t)e * 8);
  float4 a0 = ap[0], a1 = ap[1];
  f16x8 r;
  r[0] = (_Float16)logf(a0.x + 1.0f);
  r[1] = (_Float16)logf(a0.y + 1.0f);
  r[2] = (_Float16)logf(a0.z + 1.0f);
  r[3] = (_Float16)logf(a0.w + 1.0f);
  r[4] = (_Float16)logf(a1.x + 1.0f);
  r[5] = (_Float16)logf(a1.y + 1.0f);
  r[6] = (_Float16)logf(a1.z + 1.0f);
  r[7] = (_Float16)logf(a1.w + 1.0f);
  *(f16x8*)(ea_h + (size_t)pos * 8) = r;
}

// ---------------- weight transpose+f16: Wt[m][n][k] = W[m..][k][n] ----------
__global__ void k_prep_w(const float* __restrict__ W1, const float* __restrict__ W2,
                         const float* __restrict__ W3, _Float16* __restrict__ Wt) {
  __shared__ _Float16 t[128][130];
  int m = blockIdx.x;  // 0..44 = blk*3+layer
  int blk = m / 3, layer = m % 3;
  const float* src = (layer == 0 ? W1 : layer == 1 ? W2 : W3) + (size_t)blk * 16384;
  int tid = threadIdx.x;
  for (int idx = tid; idx < 16384; idx += 256) {
    int k = idx >> 7, n = idx & 127;
    t[k][n] = (_Float16)src[idx];
  }
  __syncthreads();
  _Float16* dst = Wt + (size_t)m * 16384;
  for (int idx = tid; idx < 16384; idx += 256) {
    int n = idx >> 7, k = idx & 127;
    dst[idx] = t[k][n];
  }
}

// -------- per-block message+aggregate (f16 gather, fp32 math, 4-deep ILP) ----
__global__ __launch_bounds__(256) void k_msg(
    const int* __restrict__ off, const int* __restrict__ src_s,
    const _Float16* __restrict__ ea_h, const _Float16* __restrict__ x2h,
    const float* __restrict__ eW, const float* __restrict__ ebias,
    _Float16* __restrict__ z_h) {
  int wid = (blockIdx.x * blockDim.x + threadIdx.x) >> 6;
  int lane = threadIdx.x & 63;
  if (wid >= N_NODES) return;
  int c0 = lane, c1 = lane + 64;
  float w0[EDGE_DIM], w1[EDGE_DIM];
#pragma unroll
  for (int k = 0; k < EDGE_DIM; k++) {
    w0[k] = eW[k * N_HIDDEN + c0];
    w1[k] = eW[k * N_HIDDEN + c1];
  }
  float bb0 = ebias[c0], bb1 = ebias[c1];
  float acc0 = 0.f, acc1 = 0.f;
  int eBeg = off[wid], eEnd = off[wid + 1];

#define EDGE_COMPUTE(EV, UA, UB)                                               \
  {                                                                            \
    float e0 = (float)(EV)[0], e1 = (float)(EV)[1], e2 = (float)(EV)[2],       \
          e3 = (float)(EV)[3], e4 = (float)(EV)[4], e5 = (float)(EV)[5],       \
          e6 = (float)(EV)[6], e7 = (float)(EV)[7];                            \
    float v0 = bb0 + e0 * w0[0] + e1 * w0[1] + e2 * w0[2] + e3 * w0[3] +       \
               e4 * w0[4] + e5 * w0[5] + e6 * w0[6] + e7 * w0[7];              \
    float v1 = bb1 + e0 * w1[0] + e1 * w1[1] + e2 * w1[2] + e3 * w1[3] +       \
               e4 * w1[4] + e5 * w1[5] + e6 * w1[6] + e7 * w1[7];              \
    acc0 += fmaxf((float)(UA) + v0, 0.f);                                      \
    acc1 += fmaxf((float)(UB) + v1, 0.f);                                      \
  }

  int e = eBeg;
  for (; e + 3 < eEnd; e += 4) {
    int s0 = src_s[e], s1 = src_s[e + 1], s2 = src_s[e + 2], s3 = src_s[e + 3];
    f16x8 ev0 = *(const f16x8*)(ea_h + (size_t)e * 8);
    f16x8 ev1 = *(const f16x8*)(ea_h + (size_t)(e + 1) * 8);
    f16x8 ev2 = *(const f16x8*)(ea_h + (size_t)(e + 2) * 8);
    f16x8 ev3 = *(const f16x8*)(ea_h + (size_t)(e + 3) * 8);
    _Float16 ua0 = x2h[(size_t)s0 * 128 + c0], ub0 = x2h[(size_t)s0 * 128 + c1];
    _Float16 ua1 = x2h[(size_t)s1 * 128 + c0], ub1 = x2h[(size_t)s1 * 128 + c1];
    _Float16 ua2 = x2h[(size_t)s2 * 128 + c0], ub2 = x2h[(size_t)s2 * 128 + c1];
    _Float16 ua3 = x2h[(size_t)s3 * 128 + c0], ub3 = x2h[(size_t)s3 * 128 + c1];
    EDGE_COMPUTE(ev0, ua0, ub0);
    EDGE_COMPUTE(ev1, ua1, ub1);
    EDGE_COMPUTE(ev2, ua2, ub2);
    EDGE_COMPUTE(ev3, ua3, ub3);
  }
  for (; e < eEnd; ++e) {
    int s = src_s[e];
    f16x8 ev = *(const f16x8*)(ea_h + (size_t)e * 8);
    _Float16 ua = x2h[(size_t)s * 128 + c0], ub = x2h[(size_t)s * 128 + c1];
    EDGE_COMPUTE(ev, ua, ub);
  }
#undef EDGE_COMPUTE

  size_t o = (size_t)wid * N_HIDDEN;
  z_h[o + c0] = (_Float16)((float)x2h[o + c0] + acc0);
  z_h[o + c1] = (_Float16)((float)x2h[o + c1] + acc1);
}

// -------- MFMA MLP: 64 nodes/block, 4 waves, wave owns 16 rows ---------------
__global__ __launch_bounds__(256) void k_mlp(
    const _Float16* __restrict__ z_h, const _Float16* __restrict__ Wt,
    const float* __restrict__ b1, const float* __restrict__ b2,
    const float* __restrict__ b3, float* __restrict__ h,
    _Float16* __restrict__ x2h) {
  __shared__ __align__(16) _Float16 lz[4][16][136];  // per-wave private
  int tid = threadIdx.x;
  int w = tid >> 6, lane = tid & 63;
  int l15 = lane & 15, g = lane >> 4;
  int g0 = blockIdx.x * 64;
  int nodeA = g0 + w * 16 + l15;
  int nodeAc = min(nodeA, N_NODES - 1);

  f32x4 acc[8];
  f16x8 a[4];

  // ---- layer 1: A from global z_h ----
#pragma unroll
  for (int kk = 0; kk < 4; kk++)
    a[kk] = *(const f16x8*)(z_h + (size_t)nodeAc * 128 + kk * 32 + g * 8);
#pragma unroll
  for (int c = 0; c < 8; c++) {
    float bv = b1[c * 16 + l15];
    acc[c] = (f32x4){bv, bv, bv, bv};
  }
#pragma unroll
  for (int c = 0; c < 8; c++) {
#pragma unroll
    for (int kk = 0; kk < 4; kk++) {
      f16x8 bf = *(const f16x8*)(Wt + (size_t)(c * 16 + l15) * 128 + kk * 32 + g * 8);
      acc[c] = __builtin_amdgcn_mfma_f32_16x16x32_f16(a[kk], bf, acc[c], 0, 0, 0);
    }
  }
#pragma unroll
  for (int c = 0; c < 8; c++)
#pragma unroll
    for (int r = 0; r < 4; r++)
      lz[w][4 * g + r][c * 16 + l15] = (_Float16)fmaxf(acc[c][r], 0.f);
  __syncthreads();

  // ---- layer 2: A from LDS ----
#pragma unroll
  for (int kk = 0; kk < 4; kk++)
    a[kk] = *(const f16x8*)&lz[w][l15][kk * 32 + g * 8];
#pragma unroll
  for (int c = 0; c < 8; c++) {
    float bv = b2[c * 16 + l15];
    acc[c] = (f32x4){bv, bv, bv, bv};
  }
  {
    const _Float16* W2t = Wt + 16384;
#pragma unroll
    for (int c = 0; c < 8; c++) {
#pragma unroll
      for (int kk = 0; kk < 4; kk++) {
        f16x8 bf = *(const f16x8*)(W2t + (size_t)(c * 16 + l15) * 128 + kk * 32 + g * 8);
        acc[c] = __builtin_amdgcn_mfma_f32_16x16x32_f16(a[kk], bf, acc[c], 0, 0, 0);
      }
    }
  }
  __syncthreads();
#pragma unroll
  for (int c = 0; c < 8; c++)
#pragma unroll
    for (int r = 0; r < 4; r++)
      lz[w][4 * g + r][c * 16 + l15] = (_Float16)fmaxf(acc[c][r], 0.f);
  __syncthreads();

  // ---- layer 3 (no relu) ----
#pragma unroll
  for (int kk = 0; kk < 4; kk++)
    a[kk] = *(const f16x8*)&lz[w][l15][kk * 32 + g * 8];
#pragma unroll
  for (int c = 0; c < 8; c++) {
    float bv = b3[c * 16 + l15];
    acc[c] = (f32x4){bv, bv, bv, bv};
  }
  {
    const _Float16* W3t = Wt + 32768;
#pragma unroll
    for (int c = 0; c < 8; c++) {
#pragma unroll
      for (int kk = 0; kk < 4; kk++) {
        f16x8 bf = *(const f16x8*)(W3t + (size_t)(c * 16 + l15) * 128 + kk * 32 + g * 8);
        acc[c] = __builtin_amdgcn_mfma_f32_16x16x32_f16(a[kk], bf, acc[c], 0, 0, 0);
      }
    }
  }

  // ---- epilogue: y = z3/std; h += y; x2h = f16(h/std(h)) ----
  // C/D layout: col = 16c + l15, row(node offset) = 4g + r
  float s1[4] = {0.f, 0.f, 0.f, 0.f}, s2[4] = {0.f, 0.f, 0.f, 0.f};
#pragma unroll
  for (int c = 0; c < 8; c++)
#pragma unroll
    for (int r = 0; r < 4; r++) {
      float v = acc[c][r];
      s1[r] += v;
      s2[r] += v * v;
    }
#pragma unroll
  for (int m = 1; m < 16; m <<= 1)
#pragma unroll
    for (int r = 0; r < 4; r++) {
      s1[r] += __shfl_xor(s1[r], m);
      s2[r] += __shfl_xor(s2[r], m);
    }
  float inv[4];
#pragma unroll
  for (int r = 0; r < 4; r++)
    inv[r] = 1.0f / sqrtf((s2[r] - s1[r] * s1[r] * (1.0f / 128.0f)) * (1.0f / 127.0f));

  int nodeE = g0 + w * 16 + 4 * g;
  float t1[4] = {0.f, 0.f, 0.f, 0.f}, t2[4] = {0.f, 0.f, 0.f, 0.f};
#pragma unroll
  for (int c = 0; c < 8; c++)
#pragma unroll
    for (int r = 0; r < 4; r++) {
      int n = nodeE + r;
      int nc = min(n, N_NODES - 1);
      float hv = h[(size_t)nc * 128 + c * 16 + l15] + acc[c][r] * inv[r];
      acc[c][r] = hv;
      t1[r] += hv;
      t2[r] += hv * hv;
    }
#pragma unroll
  for (int m = 1; m < 16; m <<= 1)
#pragma unroll
    for (int r = 0; r < 4; r++) {
      t1[r] += __shfl_xor(t1[r], m);
      t2[r] += __shfl_xor(t2[r], m);
    }
  float inv2[4];
#pragma unroll
  for (int r = 0; r < 4; r++)
    inv2[r] = 1.0f / sqrtf((t2[r] - t1[r] * t1[r] * (1.0f / 128.0f)) * (1.0f / 127.0f));

#pragma unroll
  for (int c = 0; c < 8; c++)
#pragma unroll
    for (int r = 0; r < 4; r++) {
      int n = nodeE + r;
      if (n < N_NODES) {
        size_t idx = (size_t)n * 128 + c * 16 + l15;
        h[idx] = acc[c][r];
        x2h[idx] = (_Float16)(acc[c][r] * inv2[r]);
      }
    }
}

// -------- output --------
__global__ void k_out(const float* __restrict__ h, const float* __restrict__ oW,
                      const float* __restrict__ ob, float* __restrict__ out) {
  int wid = (blockIdx.x * blockDim.x + threadIdx.x) >> 6;
  int lane = threadIdx.x & 63;
  if (wid >= N_NODES) return;
  int c0 = lane, c1 = lane + 64;
  float w0 = 0.f, w1 = 0.f, bsum = 0.f;
#pragma unroll
  for (int j = 0; j < N_BINARY; j++) {
    float sc = (float)(1 << j);
    w0 += oW[c0 * N_BINARY + j] * sc;
    w1 += oW[c1 * N_BINARY + j] * sc;
    bsum += ob[j] * sc;
  }
  size_t o = (size_t)wid * 128;
  float v = h[o + c0] * w0 + h[o + c1] * w1;
#pragma unroll
  for (int m = 1; m < 64; m <<= 1) v += __shfl_xor(v, m);
  if (lane == 0) out[wid] = v * (1.0f / sqrtf(15.0f)) + bsum;
}

extern "C" void kernel_launch(void* const* d_in, const int* in_sizes, int n_in,
                              void* d_out, int out_size, void* d_ws, size_t ws_size,
                              hipStream_t stream) {
  const float* x = (const float*)d_in[0];
  const int* ei = (const int*)d_in[1];
  const float* eattr = (const float*)d_in[2];
  const float* embW = (const float*)d_in[3];
  const float* embB = (const float*)d_in[4];
  const float* edgeW = (const float*)d_in[5];
  const float* edgeB = (const float*)d_in[6];
  const float* W1 = (const float*)d_in[7];
  const float* b1 = (const float*)d_in[8];
  const float* W2 = (const float*)d_in[9];
  const float* b2 = (const float*)d_in[10];
  const float* W3 = (const float*)d_in[11];
  const float* b3 = (const float*)d_in[12];
  const float* outW = (const float*)d_in[13];
  const float* outB = (const float*)d_in[14];
  float* out = (float*)d_out;

  char* base = (char*)d_ws;
  size_t o = 0;
  auto carve = [&](size_t bytes) {
    size_t start = o;
    o = (start + bytes + 255) & ~(size_t)255;
    return (void*)(base + start);
  };
  int* deg = (int*)carve(N_NODES * sizeof(int));
  int* off = (int*)carve((N_NODES + 1) * sizeof(int));
  int* cur = (int*)carve(N_NODES * sizeof(int));
  int* src_s = (int*)carve(N_EDGES * sizeof(int));
  _Float16* ea_h = (_Float16*)carve((size_t)N_EDGES * EDGE_DIM * 2);
  _Float16* x2h = (_Float16*)carve((size_t)N_NODES * N_HIDDEN * 2);
  _Float16* z_h = (_Float16*)carve((size_t)N_NODES * N_HIDDEN * 2);
  float* h = (float*)carve((size_t)N_NODES * N_HIDDEN * sizeof(float));
  _Float16* Wt = (_Float16*)carve((size_t)45 * 16384 * 2);

  hipMemsetAsync(deg, 0, N_NODES * sizeof(int), stream);
  k_embed<<<N_NODES / 4, 256, 0, stream>>>(x, embW, embB, h, x2h);
  k_count<<<(N_EDGES + 255) / 256, 256, 0, stream>>>(ei, deg);
  k_scan<<<1, 1024, 0, stream>>>(deg, off, cur);
  k_permute<<<(N_EDGES + 255) / 256, 256, 0, stream>>>(ei, eattr, cur, src_s, ea_h);
  k_prep_w<<<45, 256, 0, stream>>>(W1, W2, W3, Wt);

  for (int b = 0; b < N_BLOCKS; b++) {
    k_msg<<<N_NODES / 4, 256, 0, stream>>>(off, src_s, ea_h, x2h,
                                           edgeW + (size_t)b * EDGE_DIM * N_HIDDEN,
                                           edgeB + (size_t)b * N_HIDDEN, z_h);
    k_mlp<<<(N_NODES + 63) / 64, 256, 0, stream>>>(
        z_h, Wt + (size_t)b * 3 * 16384, b1 + (size_t)b * N_HIDDEN,
        b2 + (size_t)b * N_HIDDEN, b3 + (size_t)b * N_HIDDEN, h, x2h);
  }
  k_out<<<N_NODES / 4, 256, 0, stream>>>(h, outW, outB, out);
}